// Round 9
// baseline (121.373 us; speedup 1.0000x reference)
//
#include <hip/hip_runtime.h>
#include <hip/hip_bf16.h>
#include <stdint.h>

// WTA dropout: per image keep values >= k-th largest (k = ceil(N*0.1)), zero rest.
// Exact radix select. Round-9: (1) k_scan fused into k_mask (each block
// redundantly scans the L2-hot 1MB hist; kills a dispatch + drain bubble);
// (2) k_hist uses packed u16-pair LDS hist (16KB -> 8 blocks/CU, BPI_H 64).

#define IMGS    32
#define NPER    1048576             // 2^20 elements per image
#define NPER4   (NPER / 4)          // 2^18 float4 per image
#define NBINS   8192                // 13-bit stage-1 bins
#define HWORDS  4096                // packed u16 pairs in LDS
#define BPI_H   64                  // blocks per image, hist kernel
#define BPI_M   64                  // blocks per image, mask kernel
#define CAP     16384               // global candidate capacity per image (~11.5k expected)
#define LCAP    2048                // per-block LDS candidate capacity (~180 expected)
#define CSTRIDE 64                  // counters padded to 256 B apart

typedef float floatx4 __attribute__((ext_vector_type(4)));

__device__ __forceinline__ unsigned mapf(float f) {
    unsigned u = __float_as_uint(f);
    return (u & 0x80000000u) ? ~u : (u | 0x80000000u);   // monotonic float->uint
}

// Block-wide inclusive prefix sum over 256 values (one per thread), result in p[].
__device__ __forceinline__ void block_scan256(unsigned* p, int t, unsigned v) {
    p[t] = v;
    __syncthreads();
    #pragma unroll
    for (int off = 1; off < 256; off <<= 1) {
        unsigned u = (t >= off) ? p[t - off] : 0u;
        __syncthreads();
        p[t] += u;
        __syncthreads();
    }
}

// ---------------- K0: zero hist + counters (uint4 stores) --------------------
__global__ void k_zero(uint4* __restrict__ p, int n16) {
    int i = blockIdx.x * blockDim.x + threadIdx.x;
    if (i < n16) p[i] = make_uint4(0u, 0u, 0u, 0u);
}

// ------ K1: per-image 13-bit histogram, packed u16-pair LDS (16 KB) ----------
__global__ void k_hist(const float4* __restrict__ x4, unsigned* __restrict__ hist) {
    __shared__ unsigned h[HWORDS];              // bin b -> word b>>1, half b&1
    int t = threadIdx.x;
    for (int j = t; j < HWORDS; j += 256) h[j] = 0u;
    __syncthreads();

    int bx = blockIdx.x;
    int img = bx >> 6;                          // BPI_H = 64
    long long base4 = (long long)img * NPER4 + (long long)(bx & 63) * 4096;
    // 2-deep software pipeline; per-block bin count <= 32768 so u16 never carries
    float4 v0 = x4[base4 + t];
    for (int it = 0; it < 15; ++it) {
        float4 v1 = x4[base4 + (it + 1) * 256 + t];
        unsigned b;
        b = mapf(v0.x) >> 19; atomicAdd(&h[b >> 1], 1u << ((b & 1) << 4));
        b = mapf(v0.y) >> 19; atomicAdd(&h[b >> 1], 1u << ((b & 1) << 4));
        b = mapf(v0.z) >> 19; atomicAdd(&h[b >> 1], 1u << ((b & 1) << 4));
        b = mapf(v0.w) >> 19; atomicAdd(&h[b >> 1], 1u << ((b & 1) << 4));
        v0 = v1;
    }
    {
        unsigned b;
        b = mapf(v0.x) >> 19; atomicAdd(&h[b >> 1], 1u << ((b & 1) << 4));
        b = mapf(v0.y) >> 19; atomicAdd(&h[b >> 1], 1u << ((b & 1) << 4));
        b = mapf(v0.z) >> 19; atomicAdd(&h[b >> 1], 1u << ((b & 1) << 4));
        b = mapf(v0.w) >> 19; atomicAdd(&h[b >> 1], 1u << ((b & 1) << 4));
    }
    __syncthreads();

    unsigned* gh = hist + (long long)img * NBINS;
    for (int w = t; w < HWORDS; w += 256) {
        unsigned v = h[w];
        unsigned c0 = v & 0xFFFFu, c1 = v >> 16;
        if (c0) atomicAdd(&gh[2 * w], c0);
        if (c1) atomicAdd(&gh[2 * w + 1], c1);
    }
}

// -- K2: per-block redundant threshold scan + mask + candidate collection -----
__global__ void k_mask(const float4* __restrict__ x4, float4* __restrict__ o4,
                       const unsigned* __restrict__ hist, uint2* __restrict__ binfo,
                       unsigned* __restrict__ counters,
                       unsigned* __restrict__ candKey, unsigned* __restrict__ candIdx,
                       unsigned k) {
    __shared__ unsigned lkey[LCAP];
    __shared__ unsigned lidx[LCAP];
    __shared__ unsigned pre[256];
    __shared__ unsigned lcnt, gbase, sb13, sr;
    int t = threadIdx.x;

    int bx = blockIdx.x;
    int img = bx >> 6;                          // BPI_M = 64
    const unsigned* gh = hist + (long long)img * NBINS;

    // ---- fused scan: find bin b13 containing k-th largest (L2-hot reads) ----
    unsigned s = 0;
    #pragma unroll
    for (int j = 0; j < 32; ++j) s += gh[t * 32 + j];   // own 128B line
    block_scan256(pre, t, s);
    unsigned above = pre[255] - pre[t];         // mass in higher-valued chunks
    if (above < k && above + s >= k) {
        unsigned cum = above;
        for (int j = 31; j >= 0; --j) {
            unsigned v = gh[t * 32 + j];
            cum += v;
            if (cum >= k) {
                sb13 = (unsigned)(t * 32 + j);
                sr = k - (cum - v);             // rank within bin, in [1, hv]
                break;
            }
        }
    }
    if (t == 0) lcnt = 0u;
    __syncthreads();
    unsigned b13 = sb13;
    if ((bx & 63) == 0 && t == 0) binfo[img] = make_uint2(sb13, sr); // for K3

    // ---- mask pass ----
    long long base4 = (long long)img * NPER4 + (long long)(bx & 63) * 4096;
    for (int it = 0; it < 16; ++it) {
        long long i = base4 + it * 256 + t;
        float4 v = x4[i];
        unsigned ebase = (unsigned)(i & (NPER4 - 1)) * 4u;
        float4 o;
        float* vp = &v.x;
        float* op = &o.x;
        #pragma unroll
        for (int j = 0; j < 4; ++j) {
            float c = vp[j];
            unsigned key = mapf(c);
            unsigned t13 = key >> 19;
            op[j] = (t13 >= b13) ? c : 0.0f;     // boundary bin: provisional keep
            if (t13 == b13) {
                unsigned p = atomicAdd(&lcnt, 1u);   // LDS atomic: cheap
                if (p < LCAP) { lkey[p] = key; lidx[p] = ebase + (unsigned)j; }
            }
        }
        floatx4 ov = { o.x, o.y, o.z, o.w };     // write-once stream: bypass L2
        __builtin_nontemporal_store(ov, (floatx4*)&o4[i]);
    }
    __syncthreads();

    unsigned n = lcnt;
    if (n > LCAP) n = LCAP;
    if (t == 0) gbase = atomicAdd(&counters[img * CSTRIDE], n);  // ONE per block
    __syncthreads();
    unsigned gb = gbase;
    long long cb = (long long)img * CAP;
    for (unsigned j = t; j < n; j += 256u) {
        unsigned pos = gb + j;
        if (pos < CAP) {
            candKey[cb + pos] = lkey[j];
            candIdx[cb + pos] = lidx[j];
        }
    }
}

// ---- K3: 2-round block-parallel refine (11b then 8b) + exact fixup ----------
__global__ void k_select_fix(float* __restrict__ out,
                             const uint2* __restrict__ binfo,
                             const unsigned* __restrict__ counters,
                             const unsigned* __restrict__ candKey,
                             const unsigned* __restrict__ candIdx) {
    int img = blockIdx.x;
    __shared__ unsigned klds[CAP];              // 64 KB candidate keys (low 19 bits)
    __shared__ unsigned h2[2048];               // 8 KB: 11-bit bins
    __shared__ unsigned h256[256];
    __shared__ unsigned pre[256];
    __shared__ unsigned sh_p11, sh_r2, sh_thr;
    int t = threadIdx.x;

    unsigned cnt = counters[img * CSTRIDE];
    if (cnt > CAP) cnt = CAP;
    unsigned r = binfo[img].y;
    const unsigned* ck = candKey + (long long)img * CAP;
    const unsigned* ci = candIdx + (long long)img * CAP;

    for (int j = t; j < 2048; j += 256) h2[j] = 0u;
    __syncthreads();

    // load keys -> LDS once; round-1 histogram on bits [18:8]
    for (unsigned j = t; j < cnt; j += 256u) {
        unsigned kl = ck[j] & 0x7FFFFu;
        klds[j] = kl;
        atomicAdd(&h2[kl >> 8], 1u);
    }
    __syncthreads();

    unsigned s = 0;
    #pragma unroll
    for (int j = 0; j < 8; ++j) s += h2[t * 8 + ((j + t) & 7)];
    block_scan256(pre, t, s);
    unsigned above = pre[255] - pre[t];
    if (above < r && above + s >= r) {
        unsigned cum = above;
        for (int j = 7; j >= 0; --j) {
            unsigned v = h2[t * 8 + j];
            cum += v;
            if (cum >= r) {
                sh_p11 = (unsigned)(t * 8 + j);
                sh_r2 = r - (cum - v);
                break;
            }
        }
    }
    __syncthreads();
    unsigned p11 = sh_p11, r2 = sh_r2;

    h256[t] = 0u;
    __syncthreads();
    for (unsigned j = t; j < cnt; j += 256u) {
        unsigned kl = klds[j];
        if ((kl >> 8) == p11) atomicAdd(&h256[kl & 0xFFu], 1u);
    }
    __syncthreads();
    unsigned v = h256[t];                       // thread t owns bin t
    block_scan256(pre, t, v);
    unsigned above2 = pre[255] - pre[t];
    if (above2 < r2 && above2 + v >= r2)
        sh_thr = (p11 << 8) | (unsigned)t;      // exact low-19 bits of k-th largest
    __syncthreads();
    unsigned thr = sh_thr;

    float* oi = out + (long long)img * NPER;
    for (unsigned j = t; j < cnt; j += 256u) {
        if (klds[j] < thr) oi[ci[j]] = 0.0f;
    }
}

extern "C" void kernel_launch(void* const* d_in, const int* in_sizes, int n_in,
                              void* d_out, int out_size, void* d_ws, size_t ws_size,
                              hipStream_t stream) {
    const float* x = (const float*)d_in[0];
    float* out = (float*)d_out;
    unsigned k = (unsigned)((NPER + 9) / 10);         // ceil(N*0.1) = 104858

    // workspace layout
    char* ws = (char*)d_ws;
    size_t histB = (size_t)IMGS * NBINS * 4;                         // 1 MB
    size_t cntB  = (size_t)IMGS * CSTRIDE * 4;                       // 8 KB
    unsigned* hist     = (unsigned*)ws;
    unsigned* counters = (unsigned*)(ws + histB);
    uint2*    binfo    = (uint2*)   (ws + histB + cntB);
    unsigned* candKey  = (unsigned*)(ws + histB + cntB + 1024);      // 2 MB
    unsigned* candIdx  = (unsigned*)(ws + histB + cntB + 1024
                                        + (size_t)IMGS * CAP * 4);   // 2 MB

    // zero hist + counters with our own kernel
    int n16 = (int)((histB + cntB) / 16);
    k_zero<<<dim3((n16 + 255) / 256), dim3(256), 0, stream>>>((uint4*)ws, n16);

    dim3 blk(256);
    k_hist<<<dim3(IMGS * BPI_H), blk, 0, stream>>>((const float4*)x, hist);
    k_mask<<<dim3(IMGS * BPI_M), blk, 0, stream>>>((const float4*)x, (float4*)out,
                                                   hist, binfo, counters,
                                                   candKey, candIdx, k);
    k_select_fix<<<dim3(IMGS), blk, 0, stream>>>(out, binfo, counters, candKey, candIdx);
}